// Round 14
// baseline (613.117 us; speedup 1.0000x reference)
//
#include <hip/hip_runtime.h>
#include <hip/hip_bf16.h>

#define N_NODES 100000
#define NPAD    100096          // 782 * 128
#define NRB     782
#define E_EDGES 1600000
#define NBLK_SCAN 98

// histogram-degree params
#define HNR  4
#define HP   64
#define HCHK 25000
#define HRSZ 32768

// bucketed-fill params
#define NBK  196
#define PCHK 6250

#define AS1 __attribute__((address_space(1)))
#define AS3 __attribute__((address_space(3)))

typedef unsigned int   uint;
typedef unsigned short ushort;
typedef __attribute__((ext_vector_type(8))) short bfx8;
typedef __attribute__((ext_vector_type(4))) float fx4;

__device__ __forceinline__ float bf2f(ushort u) {
    return __uint_as_float(((uint)u) << 16);
}
__device__ __forceinline__ ushort f2bf(float f) {
    uint x = __float_as_uint(f);
    return (ushort)((x + 0x7FFFu + ((x >> 16) & 1u)) >> 16);   // RNE
}
__device__ __forceinline__ float gelu_fast(float x) {
    float u = 1.5957691f * __builtin_fmaf(0.044715f * x * x, x, x);
    return x * __builtin_amdgcn_rcpf(1.0f + __expf(-u));
}
__device__ __forceinline__ float wave_sum(float v) {
    #pragma unroll
    for (int m = 1; m < 64; m <<= 1) v += __shfl_xor(v, m, 64);
    return v;
}
__device__ __forceinline__ int xcd_swz(int orig, int nwg) {
    int q = nwg >> 3, r = nwg & 7;
    int x = orig & 7, o = orig >> 3;
    return (x < r ? x * (q + 1) : r * (q + 1) + (x - r) * q) + o;
}

// ---------------- degrees via LDS histograms (src+dst in one launch) ----------------
__global__ void k_hist2(const int* __restrict__ src, const int* __restrict__ dst,
                        uint* __restrict__ partO, uint* __restrict__ partI)
{
    __shared__ uint h[HRSZ / 2];
    int half = blockIdx.x >> 8;
    int bb = blockIdx.x & 255;
    const int* idx = half ? dst : src;
    uint* part = half ? partI : partO;
    int c = bb & (HP - 1);
    int r = bb / HP;
    int t = threadIdx.x;
    for (int i = t; i < HRSZ / 2; i += 256) h[i] = 0u;
    __syncthreads();
    int base = r << 15;
    int e0 = c * HCHK;
    for (int e = e0 + t; e < e0 + HCHK; e += 256) {
        int v = idx[e] - base;
        if ((uint)v < (uint)HRSZ)
            atomicAdd(&h[v >> 1], 1u << ((v & 1) * 16));
    }
    __syncthreads();
    uint* dstp = part + ((size_t)bb << 14);
    for (int i = t; i < HRSZ / 2; i += 256) dstp[i] = h[i];
}

__global__ void k_degmerge(const uint* __restrict__ partO, const uint* __restrict__ partI,
                           int* __restrict__ inc, float* __restrict__ oscale,
                           float* __restrict__ ininv)
{
    int n = blockIdx.x * 256 + threadIdx.x;
    if (n >= NPAD) return;
    int r = n >> 15, i = (n & 32767) >> 1, hi = (n & 1) * 16;
    const uint* po = partO + ((size_t)(r * HP) << 14) + i;
    const uint* pi = partI + ((size_t)(r * HP) << 14) + i;
    uint so = 0, si = 0;
    for (int c = 0; c < HP; ++c) {
        so += (po[(size_t)c << 14] >> hi) & 0xffffu;
        si += (pi[(size_t)c << 14] >> hi) & 0xffffu;
    }
    inc[n] = (int)si;
    oscale[n] = rsqrtf((float)max((int)so, 1));
    ininv[n] = rsqrtf((float)max((int)si, 1));
}

// ---------------- CSR scan ----------------
__global__ void k_scan1(const int* __restrict__ inc, int* __restrict__ coff, int* __restrict__ btot)
{
    __shared__ int a[1024], bsh[1024];
    int t = threadIdx.x;
    int i = blockIdx.x * 1024 + t;
    a[t] = (i < N_NODES) ? inc[i] : 0;
    __syncthreads();
    int* s = a; int* d = bsh;
    for (int dd = 1; dd < 1024; dd <<= 1) {
        int v = s[t] + ((t >= dd) ? s[t - dd] : 0);
        d[t] = v;
        __syncthreads();
        int* tmp = s; s = d; d = tmp;
    }
    if (i < N_NODES) coff[i + 1] = s[t];
    if (t == 1023) btot[blockIdx.x] = s[t];
}

__global__ void k_scan2(int* __restrict__ btot)
{
    __shared__ int a[128], bsh[128];
    int t = threadIdx.x;
    a[t] = (t < NBLK_SCAN) ? btot[t] : 0;
    __syncthreads();
    int* s = a; int* d = bsh;
    for (int dd = 1; dd < 128; dd <<= 1) {
        int v = s[t] + ((t >= dd) ? s[t - dd] : 0);
        d[t] = v;
        __syncthreads();
        int* tmp = s; s = d; d = tmp;
    }
    if (t < NBLK_SCAN) btot[t] = s[t];
}

__global__ void k_scan3(int* __restrict__ coff, const int* __restrict__ btot,
                        int* __restrict__ gcur)
{
    int i = blockIdx.x * 256 + threadIdx.x;
    if (i == 0) { coff[0] = 0; gcur[0] = 0; }
    if (i < N_NODES) {
        int blk = i >> 10;
        int v = coff[i + 1];
        if (blk > 0) v += btot[blk - 1];
        coff[i + 1] = v;
        if (((i + 1) & 511) == 0) {
            int t = (i + 1) >> 9;
            if (t < NBK) gcur[t] = v;
        }
    }
}

// ---------------- bucketed edge fill ----------------
__global__ __launch_bounds__(256) void k_part(const int* __restrict__ src, const int* __restrict__ dst,
                                              int* __restrict__ gcur, uint* __restrict__ tmp)
{
    __shared__ int cnt[NBK], rcnt[NBK], base[NBK], loff[NBK];
    __shared__ int sa[256], sb[256];
    __shared__ uint arr[PCHK];
    int t = threadIdx.x;
    if (t < NBK) { cnt[t] = 0; rcnt[t] = 0; }
    __syncthreads();
    int e0 = blockIdx.x * PCHK;
    for (int e = e0 + t; e < e0 + PCHK; e += 256)
        atomicAdd(&cnt[dst[e] >> 9], 1);
    __syncthreads();
    sa[t] = (t < NBK) ? cnt[t] : 0;
    __syncthreads();
    int* s = sa; int* d = sb;
    for (int dd = 1; dd < 256; dd <<= 1) {
        int v = s[t] + ((t >= dd) ? s[t - dd] : 0);
        d[t] = v;
        __syncthreads();
        int* w = s; s = d; d = w;
    }
    if (t < NBK) {
        loff[t] = s[t] - cnt[t];
        base[t] = atomicAdd(&gcur[t], cnt[t]);
    }
    __syncthreads();
    for (int e = e0 + t; e < e0 + PCHK; e += 256) {
        int dv = dst[e];
        int b = dv >> 9;
        int r = atomicAdd(&rcnt[b], 1);
        arr[loff[b] + r] = ((uint)src[e] << 9) | (uint)(dv & 511);
    }
    __syncthreads();
    for (int b = 0; b < NBK; ++b) {
        int n = cnt[b], lo = loff[b], gb = base[b];
        for (int i = t; i < n; i += 256)
            tmp[gb + i] = arr[lo + i];
    }
}

__global__ __launch_bounds__(256) void k_fill2(const uint* __restrict__ tmp, const int* __restrict__ coff,
                                               int* __restrict__ eidx)
{
    __shared__ int lco[512];
    __shared__ int lcnt[512];
    int b = blockIdx.x, t = threadIdx.x;
    int n0 = b << 9;
    for (int i = t; i < 512; i += 256) {
        int node = n0 + i;
        lco[i] = (node <= N_NODES) ? coff[node] : E_EDGES;
        lcnt[i] = 0;
    }
    __syncthreads();
    int s0 = coff[n0];
    int s1 = (n0 + 512 <= N_NODES) ? coff[n0 + 512] : E_EDGES;
    for (int e = s0 + t; e < s1; e += 256) {
        uint v = tmp[e];
        int dl = v & 511;
        int r = atomicAdd(&lcnt[dl], 1);
        eidx[lco[dl] + r] = (int)(v >> 9);
    }
}

// xh[r,:] = bf16(x[r,:] * oscale[r])
__global__ void k_xhat(const float* __restrict__ x, const float* __restrict__ oscale,
                       ushort* __restrict__ xh)
{
    size_t i = (size_t)blockIdx.x * 256 + threadIdx.x;
    size_t e0 = i * 4;
    int row = (int)(e0 >> 7);
    uint2 o;
    if (row < N_NODES) {
        float4 v = *(const float4*)(x + e0);
        float s = oscale[row];
        o.x = (uint)f2bf(v.x * s) | ((uint)f2bf(v.y * s) << 16);
        o.y = (uint)f2bf(v.z * s) | ((uint)f2bf(v.w * s) << 16);
    } else {
        o.x = 0u; o.y = 0u;
    }
    *(uint2*)(xh + e0) = o;
}

// one wave per dst row, 4 edges in flight, 16B/lane gather
__global__ void k_agg(const int* __restrict__ off, const int* __restrict__ eidx,
                      const ushort* __restrict__ xh, ushort* __restrict__ agg)
{
    int wid = threadIdx.x >> 6, lane = threadIdx.x & 63;
    int r = blockIdx.x * 4 + wid;
    if (r >= NPAD) return;
    int f = lane & 15;
    int g = lane >> 4;
    float a[8] = {0.f, 0.f, 0.f, 0.f, 0.f, 0.f, 0.f, 0.f};
    if (r < N_NODES) {
        int s = off[r], e = off[r + 1];
        for (int i = s + g; i < e; i += 4) {
            int sv = eidx[i];
            bfx8 v = *(const bfx8*)(xh + (size_t)sv * 128 + f * 8);
            #pragma unroll
            for (int k = 0; k < 8; ++k) a[k] += bf2f((ushort)v[k]);
        }
    }
    #pragma unroll
    for (int k = 0; k < 8; ++k) {
        a[k] += __shfl_xor(a[k], 16, 64);
        a[k] += __shfl_xor(a[k], 32, 64);
    }
    if (g == 0) {
        bfx8 o;
        #pragma unroll
        for (int k = 0; k < 8; ++k) o[k] = (short)f2bf(a[k]);
        *(bfx8*)(agg + (size_t)r * 128 + f * 8) = o;
    }
}

// ---------------- all weight prep in ONE launch ----------------
__global__ void k_wprep(const float* __restrict__ gcn_w, const float* __restrict__ ff_w1,
                        const float* __restrict__ fc1_w, const float* __restrict__ ff_w2,
                        const float* __restrict__ ln_g, const float* __restrict__ ln_b,
                        const float* __restrict__ ff_b2,
                        ushort* __restrict__ gwT, ushort* __restrict__ ff1T,
                        ushort* __restrict__ fc1T, ushort* __restrict__ ff2T,
                        float* __restrict__ lnU, float* __restrict__ lnT)
{
    int bid = blockIdx.x, tid = threadIdx.x;
    if (bid < 576) {
        const float* W; ushort* Wt; int K, M, id;
        if (bid < 64)       { W = gcn_w; Wt = gwT;  K = 128; M = 128; id = bid * 256 + tid; }
        else if (bid < 320) { W = ff_w1; Wt = ff1T; K = 128; M = 512; id = (bid - 64) * 256 + tid; }
        else                { W = fc1_w; Wt = fc1T; K = 128; M = 512; id = (bid - 320) * 256 + tid; }
        int m = id / K, k = id - m * K;
        Wt[id] = f2bf(W[(size_t)k * M + m]);
    } else {
        int wid = tid >> 6, lane = tid & 63;
        int m = (bid - 576) * 4 + wid;
        float us = 0.f, ts = 0.f;
        for (int k = lane; k < 512; k += 64) {
            float w = ff_w2[(size_t)k * 128 + m];
            float gk = ln_g[k], bk = ln_b[k];
            ff2T[(size_t)m * 512 + k] = f2bf(gk * w);
            us += gk * w; ts += bk * w;
        }
        us = wave_sum(us); ts = wave_sum(ts);
        if (lane == 0) { lnU[m] = us; lnT[m] = ts + ff_b2[m]; }
    }
}

// ---------------- MEGA: GCN -> ff1(gelu) -> ff2(LN-folded, slab-fused) -> fc1(gelu, bn1 stats)
// One 128-row block does the whole chain; f never touches HBM.
// __launch_bounds__(512, 2): allow up to 256 VGPR so the persistent h2acc never spills
// (occupancy is LDS-capped at 2 blocks/CU regardless).
__global__ __launch_bounds__(512, 2) void k_mega(
    const ushort* __restrict__ A1, const ushort* __restrict__ gwT,
    const ushort* __restrict__ ff1T, const ushort* __restrict__ ff2T,
    const ushort* __restrict__ fc1T, ushort* __restrict__ M1,
    const float* __restrict__ gcn_b, const float* __restrict__ ininv,
    const float* __restrict__ b1,
    const float* __restrict__ lnU, const float* __restrict__ lnT,
    const float* __restrict__ fc1_b,
    float* __restrict__ pS, float* __restrict__ pQ)
{
    __shared__ __align__(16) char smem[65536 + 2560];
    char* A2  = smem;             // 32KB: h tile, later h2 tile ([128][256B] swizzled)
    char* S   = smem + 32768;     // 16KB: phase1 As | slab stage | f/m1 C-tile
    char* Bs2 = smem + 49152;     // 16KB: ff2T slab ([128][128B])
    float* st_s = (float*)(smem + 65536);          // [2][64]
    float* st_q = (float*)(smem + 65536 + 512);    // [2][64]
    float* rS   = (float*)(smem + 65536 + 1024);   // [128]
    float* rC   = (float*)(smem + 65536 + 1536);   // [128]

    const int rb = xcd_swz(blockIdx.x, gridDim.x);
    const int tid = threadIdx.x;
    const int lane = tid & 63;
    const int wid = tid >> 6;
    const int wr = wid >> 2;
    const int wc = wid & 3;
    const int m0 = wr * 64;
    const int frl = lane & 15;
    const int kg = lane >> 4;

    // ---------- phase 1: h = (agg @ gcn_w)*ininv + gcn_b ----------
    {
        char* As = S;
        char* Bs = A2;           // A2 bytes [0,16K) dead until h written after loop
        const int n0 = wc * 32;
        fx4 acc[4][2] = {};
        const ushort* Arow0 = A1 + (size_t)(rb * 128) * 128;

        for (int kb = 0; kb < 128; kb += 64) {
            #pragma unroll
            for (int c = 0; c < 2; ++c) {
                int b = c * 8192 + tid * 16;
                int row = b >> 7;
                int cibs = (b & 127) ^ ((row & 7) << 4);
                const char* ga = (const char*)(Arow0 + (size_t)row * 128 + kb) + cibs;
                const char* gb = (const char*)(gwT + (size_t)row * 128 + kb) + cibs;
                char* la = As + c * 8192 + (wid << 10);
                char* lb = Bs + c * 8192 + (wid << 10);
                __builtin_amdgcn_global_load_lds((const AS1 void*)ga, (AS3 void*)la, 16, 0, 0);
                __builtin_amdgcn_global_load_lds((const AS1 void*)gb, (AS3 void*)lb, 16, 0, 0);
            }
            __syncthreads();
            #pragma unroll
            for (int kk = 0; kk < 2; ++kk) {
                bfx8 av[4], bv[2];
                #pragma unroll
                for (int i = 0; i < 4; ++i) {
                    int ar = m0 + i * 16 + frl;
                    av[i] = *(const bfx8*)(As + ((ar * 128 + kk * 64 + kg * 16) ^ ((ar & 7) << 4)));
                }
                #pragma unroll
                for (int j = 0; j < 2; ++j) {
                    int br = n0 + j * 16 + frl;
                    bv[j] = *(const bfx8*)(Bs + ((br * 128 + kk * 64 + kg * 16) ^ ((br & 7) << 4)));
                }
                #pragma unroll
                for (int i = 0; i < 4; ++i)
                    #pragma unroll
                    for (int j = 0; j < 2; ++j)
                        acc[i][j] = __builtin_amdgcn_mfma_f32_16x16x32_bf16(av[i], bv[j], acc[i][j], 0, 0, 0);
            }
            __syncthreads();
        }
        #pragma unroll
        for (int j = 0; j < 2; ++j) {
            int colL = n0 + j * 16 + frl;
            float c0 = gcn_b[colL];
            #pragma unroll
            for (int i = 0; i < 4; ++i) {
                #pragma unroll
                for (int r = 0; r < 4; ++r) {
                    int rowL = m0 + i * 16 + kg * 4 + r;
                    int grow = rb * 128 + rowL;
                    float v = acc[i][j][r] * ininv[grow] + c0;
                    *(ushort*)(A2 + rowL * 256 + ((colL * 2) ^ ((rowL & 7) << 4))) = f2bf(v);
                }
            }
        }
    }
    __syncthreads();

    // ---------- phase 2: f slabs + fused h2 accumulation ----------
    float rs = 0.f, rq = 0.f;
    const int rowR = tid >> 2;
    const int qR = tid & 3;
    const int n0b = wc * 16;
    const int n0h = wc * 32;
    fx4 h2acc[4][2] = {};

    for (int cb2 = 0; cb2 < 8; ++cb2) {
        #pragma unroll
        for (int c = 0; c < 2; ++c) {
            int b = c * 8192 + tid * 16;
            int row1 = b >> 8;
            int cib1 = (b & 255) ^ ((row1 & 7) << 4);
            const char* g1 = (const char*)(ff1T + (size_t)(cb2 * 64 + row1) * 128) + cib1;
            char* l1 = S + c * 8192 + (wid << 10);
            __builtin_amdgcn_global_load_lds((const AS1 void*)g1, (AS3 void*)l1, 16, 0, 0);
            int row2 = b >> 7;
            int cib2 = (b & 127) ^ ((row2 & 7) << 4);
            const char* g2 = (const char*)ff2T + (size_t)row2 * 1024 + cb2 * 128 + cib2;
            char* l2 = Bs2 + c * 8192 + (wid << 10);
            __builtin_amdgcn_global_load_lds((const AS1 void*)g2, (AS3 void*)l2, 16, 0, 0);
        }
        __syncthreads();

        // f = h(A2) @ ff1T-slab(S)
        fx4 fa[4] = {};
        #pragma unroll
        for (int kk = 0; kk < 4; ++kk) {
            int c2 = kk * 64 + kg * 16;
            bfx8 av[4], bv;
            #pragma unroll
            for (int i = 0; i < 4; ++i) {
                int ar = m0 + i * 16 + frl;
                av[i] = *(const bfx8*)(A2 + ar * 256 + (c2 ^ ((ar & 7) << 4)));
            }
            {
                int br = n0b + frl;
                bv = *(const bfx8*)(S + br * 256 + (c2 ^ ((br & 7) << 4)));
            }
            #pragma unroll
            for (int i = 0; i < 4; ++i)
                fa[i] = __builtin_amdgcn_mfma_f32_16x16x32_bf16(av[i], bv, fa[i], 0, 0, 0);
        }
        __syncthreads();   // S reads done

        // gelu(f + b1) -> C-tile [128][128B] in S
        {
            int colL = n0b + frl;
            float bcol = b1[cb2 * 64 + colL];
            #pragma unroll
            for (int i = 0; i < 4; ++i) {
                #pragma unroll
                for (int r = 0; r < 4; ++r) {
                    float v = gelu_fast(fa[i][r] + bcol);
                    int rowL = m0 + i * 16 + kg * 4 + r;
                    *(ushort*)(S + rowL * 128 + ((colL * 2) ^ ((rowL & 7) << 4))) = f2bf(v);
                }
            }
        }
        __syncthreads();   // C-tile visible

        // h2acc += f(S) @ ff2T-slab(Bs2)  [K=64]; row stats from S
        #pragma unroll
        for (int kk2 = 0; kk2 < 2; ++kk2) {
            int c2b = kk2 * 64 + kg * 16;
            bfx8 av2[4], bv2[2];
            #pragma unroll
            for (int i = 0; i < 4; ++i) {
                int ar = m0 + i * 16 + frl;
                av2[i] = *(const bfx8*)(S + ar * 128 + (c2b ^ ((ar & 7) << 4)));
            }
            #pragma unroll
            for (int j = 0; j < 2; ++j) {
                int br = n0h + j * 16 + frl;
                bv2[j] = *(const bfx8*)(Bs2 + br * 128 + (c2b ^ ((br & 7) << 4)));
            }
            #pragma unroll
            for (int i = 0; i < 4; ++i)
                #pragma unroll
                for (int j = 0; j < 2; ++j)
                    h2acc[i][j] = __builtin_amdgcn_mfma_f32_16x16x32_bf16(av2[i], bv2[j], h2acc[i][j], 0, 0, 0);
        }
        #pragma unroll
        for (int ss = 0; ss < 2; ++ss) {
            int boff = rowR * 128 + ((qR * 32 + ss * 16) ^ ((rowR & 7) << 4));
            bfx8 v = *(const bfx8*)(S + boff);
            #pragma unroll
            for (int k2 = 0; k2 < 8; ++k2) {
                float f = bf2f((ushort)v[k2]);
                rs += f; rq += f * f;
            }
        }
        __syncthreads();   // S, Bs2 reads done before next slab
    }

    // row LN stats -> LDS
    rs += __shfl_xor(rs, 1, 64); rs += __shfl_xor(rs, 2, 64);
    rq += __shfl_xor(rq, 1, 64); rq += __shfl_xor(rq, 2, 64);
    if (qR == 0) {
        float mean = rs * (1.f / 512.f);
        float var = fmaxf(rq * (1.f / 512.f) - mean * mean, 0.f);
        float sr = rsqrtf(var + 1e-5f);
        rS[rowR] = sr;
        rC[rowR] = -mean * sr;
    }
    __syncthreads();

    // h2 epilogue: h2 = sr*h2acc + cr*u_col + t_col -> A2 (h dead)
    #pragma unroll
    for (int j = 0; j < 2; ++j) {
        int colL = n0h + j * 16 + frl;
        float uc = lnU[colL];
        float tc = lnT[colL];
        #pragma unroll
        for (int i = 0; i < 4; ++i) {
            #pragma unroll
            for (int r = 0; r < 4; ++r) {
                int rowL = m0 + i * 16 + kg * 4 + r;
                float v = rS[rowL] * h2acc[i][j][r] + rC[rowL] * uc + tc;
                *(ushort*)(A2 + rowL * 256 + ((colL * 2) ^ ((rowL & 7) << 4))) = f2bf(v);
            }
        }
    }
    __syncthreads();

    // ---------- phase 3: m1 = gelu(h2 @ fc1T + b) + bn1 col partials ----------
    for (int cb3 = 0; cb3 < 8; ++cb3) {
        #pragma unroll
        for (int c = 0; c < 2; ++c) {
            int b = c * 8192 + tid * 16;
            int row = b >> 8;
            int cibs = (b & 255) ^ ((row & 7) << 4);
            const char* gb = (const char*)(fc1T + (size_t)(cb3 * 64 + row) * 128) + cibs;
            char* lb = S + c * 8192 + (wid << 10);
            __builtin_amdgcn_global_load_lds((const AS1 void*)gb, (AS3 void*)lb, 16, 0, 0);
        }
        __syncthreads();

        fx4 ma[4] = {};
        #pragma unroll
        for (int kk = 0; kk < 4; ++kk) {
            int c2 = kk * 64 + kg * 16;
            bfx8 av[4], bv;
            #pragma unroll
            for (int i = 0; i < 4; ++i) {
                int ar = m0 + i * 16 + frl;
                av[i] = *(const bfx8*)(A2 + ar * 256 + (c2 ^ ((ar & 7) << 4)));
            }
            {
                int br = n0b + frl;
                bv = *(const bfx8*)(S + br * 256 + (c2 ^ ((br & 7) << 4)));
            }
            #pragma unroll
            for (int i = 0; i < 4; ++i)
                ma[i] = __builtin_amdgcn_mfma_f32_16x16x32_bf16(av[i], bv, ma[i], 0, 0, 0);
        }
        __syncthreads();

        {
            int colL = n0b + frl;
            float bcol = fc1_b[cb3 * 64 + colL];
            float sL = 0.f, qL = 0.f;
            #pragma unroll
            for (int i = 0; i < 4; ++i) {
                #pragma unroll
                for (int r = 0; r < 4; ++r) {
                    float v = gelu_fast(ma[i][r] + bcol);
                    int rowL = m0 + i * 16 + kg * 4 + r;
                    if (rb * 128 + rowL < N_NODES) { sL += v; qL += v * v; }
                    *(ushort*)(S + rowL * 128 + ((colL * 2) ^ ((rowL & 7) << 4))) = f2bf(v);
                }
            }
            sL += __shfl_xor(sL, 16, 64); sL += __shfl_xor(sL, 32, 64);
            qL += __shfl_xor(qL, 16, 64); qL += __shfl_xor(qL, 32, 64);
            if (kg == 0) {
                st_s[wr * 64 + colL] = sL;
                st_q[wr * 64 + colL] = qL;
            }
        }
        __syncthreads();

        {
            int r2 = tid >> 3;
            int s2 = tid & 7;
            #pragma unroll
            for (int pass = 0; pass < 2; ++pass) {
                int rowL = pass * 64 + r2;
                int boff = rowL * 128 + ((s2 * 16) ^ ((rowL & 7) << 4));
                bfx8 v = *(const bfx8*)(S + boff);
                *(bfx8*)((char*)(M1 + (size_t)(rb * 128 + rowL) * 512 + cb3 * 64) + s2 * 16) = v;
            }
        }
        if (tid < 64) {
            size_t pidx = ((size_t)rb * 4 + (cb3 >> 1)) * 128 + (cb3 & 1) * 64 + tid;
            pS[pidx] = st_s[tid] + st_s[64 + tid];
            pQ[pidx] = st_q[tid] + st_q[64 + tid];
        }
        __syncthreads();
    }
}

// ---------------- plain GEMM (fc2, fc3), 8-wave 512-thread ----------------
template <int EPI, int STATS>
__global__ __launch_bounds__(512, 4) void k_gemm(
    const ushort* __restrict__ A, const ushort* __restrict__ Bt,
    ushort* __restrict__ C, int K, int M,
    const float* __restrict__ colv0, const float* __restrict__ rowv0,
    float* __restrict__ pS, float* __restrict__ pQ, int grb0)
{
    __shared__ __align__(16) char smem[32768 + (STATS == 1 ? 2048 : 0)];
    char* AsB = smem;
    char* BsB = smem + 16384;
    float* st_s = (float*)(smem + 32768);
    float* st_q = (float*)(smem + 32768 + 1024);

    const int nwg = gridDim.x;
    const int wgid = xcd_swz(blockIdx.x, nwg);
    const int nCB = M >> 7;
    const int cb = wgid % nCB;
    const int rb = wgid / nCB;
    const int tid = threadIdx.x;
    const int lane = tid & 63;
    const int wid = tid >> 6;
    const int wr = wid >> 2;
    const int wc = wid & 3;
    const int m0 = wr * 64;
    const int n0 = wc * 32;
    const int frl = lane & 15;
    const int kg = lane >> 4;

    fx4 acc[4][2] = {};

    const ushort* Arow0 = A + (size_t)(rb * 128) * K;
    const ushort* Brow0 = Bt + (size_t)(cb * 128) * K;

    for (int kb = 0; kb < K; kb += 64) {
        #pragma unroll
        for (int c = 0; c < 2; ++c) {
            int b = c * 8192 + tid * 16;
            int row = b >> 7;
            int cibs = (b & 127) ^ ((row & 7) << 4);
            const char* ga = (const char*)(Arow0 + (size_t)row * K + kb) + cibs;
            const char* gb = (const char*)(Brow0 + (size_t)row * K + kb) + cibs;
            char* la = AsB + c * 8192 + (wid << 10);
            char* lb = BsB + c * 8192 + (wid << 10);
            __builtin_amdgcn_global_load_lds((const AS1 void*)ga, (AS3 void*)la, 16, 0, 0);
            __builtin_amdgcn_global_load_lds((const AS1 void*)gb, (AS3 void*)lb, 16, 0, 0);
        }
        __syncthreads();
        #pragma unroll
        for (int kk = 0; kk < 2; ++kk) {
            bfx8 av[4], bv[2];
            #pragma unroll
            for (int i = 0; i < 4; ++i) {
                int ar = m0 + i * 16 + frl;
                av[i] = *(const bfx8*)(AsB + ((ar * 128 + kk * 64 + kg * 16) ^ ((ar & 7) << 4)));
            }
            #pragma unroll
            for (int j = 0; j < 2; ++j) {
                int br = n0 + j * 16 + frl;
                bv[j] = *(const bfx8*)(BsB + ((br * 128 + kk * 64 + kg * 16) ^ ((br & 7) << 4)));
            }
            #pragma unroll
            for (int i = 0; i < 4; ++i)
                #pragma unroll
                for (int j = 0; j < 2; ++j)
                    acc[i][j] = __builtin_amdgcn_mfma_f32_16x16x32_bf16(av[i], bv[j], acc[i][j], 0, 0, 0);
        }
        __syncthreads();
    }

    #pragma unroll
    for (int j = 0; j < 2; ++j) {
        int colL = n0 + j * 16 + frl;
        float c0 = colv0[cb * 128 + colL];
        float sL = 0.f, qL = 0.f;
        #pragma unroll
        for (int i = 0; i < 4; ++i) {
            #pragma unroll
            for (int r = 0; r < 4; ++r) {
                float v = acc[i][j][r];
                int rowL = m0 + i * 16 + kg * 4 + r;
                int grow = (grb0 + rb) * 128 + rowL;
                if (EPI == 0) v = v * rowv0[grow] + c0;
                else          v = gelu_fast(v + c0);
                if (STATS == 1) {
                    if (grow < N_NODES) { sL += v; qL += v * v; }
                }
                *(ushort*)(smem + rowL * 256 + ((colL * 2) ^ ((rowL & 7) << 4))) = f2bf(v);
            }
        }
        if (STATS == 1) {
            sL += __shfl_xor(sL, 16, 64); sL += __shfl_xor(sL, 32, 64);
            qL += __shfl_xor(qL, 16, 64); qL += __shfl_xor(qL, 32, 64);
            if (kg == 0) {
                st_s[wr * 128 + colL] = sL;
                st_q[wr * 128 + colL] = qL;
            }
        }
    }
    __syncthreads();
    {
        int r2 = tid >> 4;
        int s2 = tid & 15;
        #pragma unroll
        for (int pass = 0; pass < 4; ++pass) {
            int rowL = pass * 32 + r2;
            int boff = rowL * 256 + ((s2 * 16) ^ ((rowL & 7) << 4));
            bfx8 v = *(const bfx8*)(smem + boff);
            *(bfx8*)((char*)(C + (size_t)(rb * 128 + rowL) * M + cb * 128) + s2 * 16) = v;
        }
    }
    if (STATS == 1 && tid < 128) {
        size_t pidx = ((size_t)(grb0 + rb) * nCB + cb) * 128 + tid;
        pS[pidx] = st_s[tid] + st_s[128 + tid];
        pQ[pidx] = st_q[tid] + st_q[128 + tid];
    }
}

// merge col partials -> sums: one wave per column
__global__ void k_colmerge(const float* __restrict__ pS, const float* __restrict__ pQ,
                           float* __restrict__ oS, float* __restrict__ oQ, int M)
{
    int wid = threadIdx.x >> 6, lane = threadIdx.x & 63;
    int m = blockIdx.x * 4 + wid;
    if (m >= M) return;
    int nCB = M >> 7, cb = m >> 7, colL = m & 127;
    float s = 0.f, q = 0.f;
    for (int rb = lane; rb < NRB; rb += 64) {
        size_t idx = ((size_t)rb * nCB + cb) * 128 + colL;
        s += pS[idx]; q += pQ[idx];
    }
    s = wave_sum(s); q = wave_sum(q);
    if (lane == 0) { oS[m] = s; oQ[m] = q; }
}

// fold BN(prev-layer cols) into next weight
__global__ void k_fold(const float* __restrict__ W, const float* __restrict__ bw,
                       const float* __restrict__ g, const float* __restrict__ bb,
                       const float* __restrict__ sum, const float* __restrict__ sqs,
                       int K, int M, ushort* __restrict__ WtO, float* __restrict__ bO)
{
    int wid = threadIdx.x >> 6, lane = threadIdx.x & 63;
    int m = blockIdx.x * 4 + wid;
    if (m >= M) return;
    float acc = 0.f;
    for (int k = lane; k < K; k += 64) {
        float mean = sum[k] * (1.f / (float)N_NODES);
        float var = sqs[k] * (1.f / (float)N_NODES) - mean * mean;
        float s = g[k] * rsqrtf(var + 1e-5f);
        float t = bb[k] - mean * s;
        float w = W[(size_t)k * M + m];
        WtO[(size_t)m * K + k] = f2bf(w * s);
        acc += t * w;
    }
    acc = wave_sum(acc);
    if (lane == 0) bO[m] = bw[m] + acc;
}

// out[r] = dot(m3[r,:128], w4) + b4
__global__ void k_out(const ushort* __restrict__ m3, const ushort* __restrict__ w4,
                      const float* __restrict__ b4, float* __restrict__ out)
{
    int wid = threadIdx.x >> 6, lane = threadIdx.x & 63;
    int r = blockIdx.x * 4 + wid;
    if (r >= N_NODES) return;
    uint u = *(const uint*)(m3 + (size_t)r * 128 + lane * 2);
    uint w = *(const uint*)(w4 + lane * 2);
    float acc = bf2f((ushort)(u & 0xffffu)) * bf2f((ushort)(w & 0xffffu))
              + bf2f((ushort)(u >> 16)) * bf2f((ushort)(w >> 16));
    acc = wave_sum(acc);
    if (lane == 0) out[r] = acc + b4[0];
}

extern "C" void kernel_launch(void* const* d_in, const int* in_sizes, int n_in,
                              void* d_out, int out_size, void* d_ws, size_t ws_size,
                              hipStream_t stream)
{
    const float* x     = (const float*)d_in[0];
    const int*   src   = (const int*)d_in[1];
    const int*   dst   = (const int*)d_in[2];
    const float* gcn_w = (const float*)d_in[3];
    const float* gcn_b = (const float*)d_in[4];
    const float* ff_w1 = (const float*)d_in[5];
    const float* ff_b1 = (const float*)d_in[6];
    const float* ln_g  = (const float*)d_in[7];
    const float* ln_b  = (const float*)d_in[8];
    const float* ff_w2 = (const float*)d_in[9];
    const float* ff_b2 = (const float*)d_in[10];
    const float* fc1_w = (const float*)d_in[11];
    const float* fc1_b = (const float*)d_in[12];
    const float* bn1_g = (const float*)d_in[13];
    const float* bn1_b = (const float*)d_in[14];
    const float* fc2_w = (const float*)d_in[15];
    const float* fc2_b = (const float*)d_in[16];
    const float* bn2_g = (const float*)d_in[17];
    const float* bn2_b = (const float*)d_in[18];
    const float* fc3_w = (const float*)d_in[19];
    const float* fc3_b = (const float*)d_in[20];
    const float* bn3_g = (const float*)d_in[21];
    const float* bn3_b = (const float*)d_in[22];
    const float* fc4_w = (const float*)d_in[23];
    const float* fc4_b = (const float*)d_in[24];
    float* out = (float*)d_out;
    (void)in_sizes; (void)n_in; (void)out_size;

    char* base = (char*)d_ws;
    char* p = base;
    auto alloc = [&](size_t bytes) -> char* {
        char* r = p;
        p += (bytes + 255) & ~(size_t)255;
        return r;
    };
    int*    inc    = (int*)alloc((size_t)NPAD * 4);
    int*    coff   = (int*)alloc(((size_t)NPAD + 1) * 4);
    int*    btot   = (int*)alloc(128 * 4);
    int*    gcur   = (int*)alloc(256 * 4);
    int*    eidx   = (int*)alloc((size_t)E_EDGES * 4);
    float*  oscale = (float*)alloc((size_t)NPAD * 4);
    float*  ininv  = (float*)alloc((size_t)NPAD * 4);
    float*  bns    = (float*)alloc(6 * 512 * 4);
    float*  b2p    = (float*)alloc(512 * 4);
    float*  b3p    = (float*)alloc(128 * 4);
    float*  b4p    = (float*)alloc(4);
    float*  lnU    = (float*)alloc(128 * 4);
    float*  lnT    = (float*)alloc(128 * 4);
    float*  pS     = (float*)alloc((size_t)4 * NPAD * 4);
    float*  pQ     = (float*)alloc((size_t)4 * NPAD * 4);
    ushort* gwT    = (ushort*)alloc(128 * 128 * 2);
    ushort* ff1T   = (ushort*)alloc(512 * 128 * 2);
    ushort* ff2T   = (ushort*)alloc(128 * 512 * 2);
    ushort* fc1T   = (ushort*)alloc(512 * 128 * 2);
    ushort* fc2T   = (ushort*)alloc(512 * 512 * 2);
    ushort* fc3T   = (ushort*)alloc(128 * 512 * 2);
    ushort* w4t    = (ushort*)alloc(128 * 2);
    ushort* buf1   = (ushort*)alloc((size_t)NPAD * 128 * 2);  // agg -> (fc2 chunk tmp) -> m3
    ushort* bufC   = (ushort*)alloc((size_t)NPAD * 512 * 2);  // hist parts / edge tmp -> xh -> m1 [-> m2]

    size_t used = (size_t)(p - base);
    bool   sep  = (used + (size_t)NPAD * 512 * 2) <= ws_size;
    ushort* m2  = sep ? (ushort*)alloc((size_t)NPAD * 512 * 2) : bufC;

    uint* partO = (uint*)bufC;
    uint* partI = partO + (size_t)HNR * HP * (HRSZ / 2);
    uint* etmp  = (uint*)bufC;
    ushort* xh  = bufC;
    ushort* agg = buf1;

    float* bn1s = bns;
    float* bn1q = bns + 512;
    float* bn2s = bns + 1024;
    float* bn2q = bns + 1536;
    float* bn3s = bns + 2048;
    float* bn3q = bns + 2560;

    k_hist2<<<2 * HNR * HP, 256, 0, stream>>>(src, dst, partO, partI);
    k_degmerge<<<(NPAD + 255) / 256, 256, 0, stream>>>(partO, partI, inc, oscale, ininv);
    k_scan1<<<NBLK_SCAN, 1024, 0, stream>>>(inc, coff, btot);
    k_scan2<<<1, 128, 0, stream>>>(btot);
    k_scan3<<<(N_NODES + 255) / 256, 256, 0, stream>>>(coff, btot, gcur);
    k_part<<<E_EDGES / PCHK, 256, 0, stream>>>(src, dst, gcur, etmp);
    k_fill2<<<NBK, 256, 0, stream>>>(etmp, coff, eidx);
    k_xhat<<<(NPAD / 256) * 32, 256, 0, stream>>>(x, oscale, xh);
    k_agg<<<NPAD / 4, 256, 0, stream>>>(coff, eidx, xh, agg);

    k_wprep<<<608, 256, 0, stream>>>(gcn_w, ff_w1, fc1_w, ff_w2, ln_g, ln_b, ff_b2,
                                     gwT, ff1T, fc1T, ff2T, lnU, lnT);

    // MEGA: GCN -> ff1(gelu) -> ff2(LN folded, slab-fused, no f round-trip) -> fc1(gelu)+bn1
    k_mega<<<NRB, 512, 0, stream>>>(agg, gwT, ff1T, ff2T, fc1T, bufC,
                                    gcn_b, ininv, ff_b1, lnU, lnT, fc1_b, pS, pQ);
    k_colmerge<<<128, 256, 0, stream>>>(pS, pQ, bn1s, bn1q, 512);
    k_fold<<<512 / 4, 256, 0, stream>>>(fc2_w, fc2_b, bn1_g, bn1_b, bn1s, bn1q, 512, 512, fc2T, b2p);
    // m2 = gelu(bn1(m1) @ fc2 + b) + bn2 partials
    if (sep) {
        k_gemm<1, 1><<<4 * NRB, 512, 0, stream>>>(bufC, fc2T, m2, 512, 512,
                                                  b2p, nullptr, pS, pQ, 0);
    } else {
        const int cOff[6] = {0, 195, 390, 585, 780, 782};
        for (int c = 0; c < 5; ++c) {
            int rb0 = cOff[c], nrb = cOff[c + 1] - rb0;
            k_gemm<1, 1><<<nrb * 4, 512, 0, stream>>>(bufC + (size_t)rb0 * 128 * 512, fc2T,
                                                      buf1, 512, 512,
                                                      b2p, nullptr, pS, pQ, rb0);
            hipMemcpyAsync(bufC + (size_t)rb0 * 128 * 512, buf1,
                           (size_t)nrb * 128 * 512 * 2, hipMemcpyDeviceToDevice, stream);
        }
    }
    k_colmerge<<<128, 256, 0, stream>>>(pS, pQ, bn2s, bn2q, 512);
    k_fold<<<128 / 4, 256, 0, stream>>>(fc3_w, fc3_b, bn2_g, bn2_b, bn2s, bn2q, 512, 128, fc3T, b3p);
    // m3 = gelu(bn2(m2) @ fc3 + b) + bn3 partials
    k_gemm<1, 1><<<NRB, 512, 0, stream>>>(m2, fc3T, buf1, 512, 128,
                                          b3p, nullptr, pS, pQ, 0);
    k_colmerge<<<32, 256, 0, stream>>>(pS, pQ, bn3s, bn3q, 128);
    k_fold<<<1, 256, 0, stream>>>(fc4_w, fc4_b, bn3_g, bn3_b, bn3s, bn3q, 128, 1, w4t, b4p);
    k_out<<<N_NODES / 4, 256, 0, stream>>>(buf1, w4t, b4p, out);
}

// Round 15
// 553.844 us; speedup vs baseline: 1.1070x; 1.1070x over previous
//
#include <hip/hip_runtime.h>
#include <hip/hip_bf16.h>

#define N_NODES 100000
#define NPAD    100096          // 782 * 128
#define NRB     782
#define E_EDGES 1600000
#define NBLK_SCAN 98

// histogram-degree params
#define HNR  4
#define HP   64
#define HCHK 25000
#define HRSZ 32768

// bucketed-fill params
#define NBK  196
#define PCHK 6250

#define AS1 __attribute__((address_space(1)))
#define AS3 __attribute__((address_space(3)))

typedef unsigned int   uint;
typedef unsigned short ushort;
typedef __attribute__((ext_vector_type(8))) short bfx8;
typedef __attribute__((ext_vector_type(4))) float fx4;

__device__ __forceinline__ float bf2f(ushort u) {
    return __uint_as_float(((uint)u) << 16);
}
__device__ __forceinline__ ushort f2bf(float f) {
    uint x = __float_as_uint(f);
    return (ushort)((x + 0x7FFFu + ((x >> 16) & 1u)) >> 16);   // RNE
}
__device__ __forceinline__ float gelu_fast(float x) {
    float u = 1.5957691f * __builtin_fmaf(0.044715f * x * x, x, x);
    return x * __builtin_amdgcn_rcpf(1.0f + __expf(-u));
}
__device__ __forceinline__ float wave_sum(float v) {
    #pragma unroll
    for (int m = 1; m < 64; m <<= 1) v += __shfl_xor(v, m, 64);
    return v;
}
__device__ __forceinline__ int xcd_swz(int orig, int nwg) {
    int q = nwg >> 3, r = nwg & 7;
    int x = orig & 7, o = orig >> 3;
    return (x < r ? x * (q + 1) : r * (q + 1) + (x - r) * q) + o;
}

// ---------------- degrees via LDS histograms (src+dst in one launch) ----------------
__global__ void k_hist2(const int* __restrict__ src, const int* __restrict__ dst,
                        uint* __restrict__ partO, uint* __restrict__ partI)
{
    __shared__ uint h[HRSZ / 2];
    int half = blockIdx.x >> 8;
    int bb = blockIdx.x & 255;
    const int* idx = half ? dst : src;
    uint* part = half ? partI : partO;
    int c = bb & (HP - 1);
    int r = bb / HP;
    int t = threadIdx.x;
    for (int i = t; i < HRSZ / 2; i += 256) h[i] = 0u;
    __syncthreads();
    int base = r << 15;
    int e0 = c * HCHK;
    for (int e = e0 + t; e < e0 + HCHK; e += 256) {
        int v = idx[e] - base;
        if ((uint)v < (uint)HRSZ)
            atomicAdd(&h[v >> 1], 1u << ((v & 1) * 16));
    }
    __syncthreads();
    uint* dstp = part + ((size_t)bb << 14);
    for (int i = t; i < HRSZ / 2; i += 256) dstp[i] = h[i];
}

__global__ void k_degmerge(const uint* __restrict__ partO, const uint* __restrict__ partI,
                           int* __restrict__ inc, float* __restrict__ oscale,
                           float* __restrict__ ininv)
{
    int n = blockIdx.x * 256 + threadIdx.x;
    if (n >= NPAD) return;
    int r = n >> 15, i = (n & 32767) >> 1, hi = (n & 1) * 16;
    const uint* po = partO + ((size_t)(r * HP) << 14) + i;
    const uint* pi = partI + ((size_t)(r * HP) << 14) + i;
    uint so = 0, si = 0;
    for (int c = 0; c < HP; ++c) {
        so += (po[(size_t)c << 14] >> hi) & 0xffffu;
        si += (pi[(size_t)c << 14] >> hi) & 0xffffu;
    }
    inc[n] = (int)si;
    oscale[n] = rsqrtf((float)max((int)so, 1));
    ininv[n] = rsqrtf((float)max((int)si, 1));
}

// ---------------- CSR scan ----------------
__global__ void k_scan1(const int* __restrict__ inc, int* __restrict__ coff, int* __restrict__ btot)
{
    __shared__ int a[1024], bsh[1024];
    int t = threadIdx.x;
    int i = blockIdx.x * 1024 + t;
    a[t] = (i < N_NODES) ? inc[i] : 0;
    __syncthreads();
    int* s = a; int* d = bsh;
    for (int dd = 1; dd < 1024; dd <<= 1) {
        int v = s[t] + ((t >= dd) ? s[t - dd] : 0);
        d[t] = v;
        __syncthreads();
        int* tmp = s; s = d; d = tmp;
    }
    if (i < N_NODES) coff[i + 1] = s[t];
    if (t == 1023) btot[blockIdx.x] = s[t];
}

__global__ void k_scan2(int* __restrict__ btot)
{
    __shared__ int a[128], bsh[128];
    int t = threadIdx.x;
    a[t] = (t < NBLK_SCAN) ? btot[t] : 0;
    __syncthreads();
    int* s = a; int* d = bsh;
    for (int dd = 1; dd < 128; dd <<= 1) {
        int v = s[t] + ((t >= dd) ? s[t - dd] : 0);
        d[t] = v;
        __syncthreads();
        int* tmp = s; s = d; d = tmp;
    }
    if (t < NBLK_SCAN) btot[t] = s[t];
}

__global__ void k_scan3(int* __restrict__ coff, const int* __restrict__ btot,
                        int* __restrict__ gcur)
{
    int i = blockIdx.x * 256 + threadIdx.x;
    if (i == 0) { coff[0] = 0; gcur[0] = 0; }
    if (i < N_NODES) {
        int blk = i >> 10;
        int v = coff[i + 1];
        if (blk > 0) v += btot[blk - 1];
        coff[i + 1] = v;
        if (((i + 1) & 511) == 0) {
            int t = (i + 1) >> 9;
            if (t < NBK) gcur[t] = v;
        }
    }
}

// ---------------- bucketed edge fill ----------------
__global__ __launch_bounds__(256) void k_part(const int* __restrict__ src, const int* __restrict__ dst,
                                              int* __restrict__ gcur, uint* __restrict__ tmp)
{
    __shared__ int cnt[NBK], rcnt[NBK], base[NBK], loff[NBK];
    __shared__ int sa[256], sb[256];
    __shared__ uint arr[PCHK];
    int t = threadIdx.x;
    if (t < NBK) { cnt[t] = 0; rcnt[t] = 0; }
    __syncthreads();
    int e0 = blockIdx.x * PCHK;
    for (int e = e0 + t; e < e0 + PCHK; e += 256)
        atomicAdd(&cnt[dst[e] >> 9], 1);
    __syncthreads();
    sa[t] = (t < NBK) ? cnt[t] : 0;
    __syncthreads();
    int* s = sa; int* d = sb;
    for (int dd = 1; dd < 256; dd <<= 1) {
        int v = s[t] + ((t >= dd) ? s[t - dd] : 0);
        d[t] = v;
        __syncthreads();
        int* w = s; s = d; d = w;
    }
    if (t < NBK) {
        loff[t] = s[t] - cnt[t];
        base[t] = atomicAdd(&gcur[t], cnt[t]);
    }
    __syncthreads();
    for (int e = e0 + t; e < e0 + PCHK; e += 256) {
        int dv = dst[e];
        int b = dv >> 9;
        int r = atomicAdd(&rcnt[b], 1);
        arr[loff[b] + r] = ((uint)src[e] << 9) | (uint)(dv & 511);
    }
    __syncthreads();
    for (int b = 0; b < NBK; ++b) {
        int n = cnt[b], lo = loff[b], gb = base[b];
        for (int i = t; i < n; i += 256)
            tmp[gb + i] = arr[lo + i];
    }
}

__global__ __launch_bounds__(256) void k_fill2(const uint* __restrict__ tmp, const int* __restrict__ coff,
                                               int* __restrict__ eidx)
{
    __shared__ int lco[512];
    __shared__ int lcnt[512];
    int b = blockIdx.x, t = threadIdx.x;
    int n0 = b << 9;
    for (int i = t; i < 512; i += 256) {
        int node = n0 + i;
        lco[i] = (node <= N_NODES) ? coff[node] : E_EDGES;
        lcnt[i] = 0;
    }
    __syncthreads();
    int s0 = coff[n0];
    int s1 = (n0 + 512 <= N_NODES) ? coff[n0 + 512] : E_EDGES;
    for (int e = s0 + t; e < s1; e += 256) {
        uint v = tmp[e];
        int dl = v & 511;
        int r = atomicAdd(&lcnt[dl], 1);
        eidx[lco[dl] + r] = (int)(v >> 9);
    }
}

// xh[r,:] = bf16(x[r,:] * oscale[r])
__global__ void k_xhat(const float* __restrict__ x, const float* __restrict__ oscale,
                       ushort* __restrict__ xh)
{
    size_t i = (size_t)blockIdx.x * 256 + threadIdx.x;
    size_t e0 = i * 4;
    int row = (int)(e0 >> 7);
    uint2 o;
    if (row < N_NODES) {
        float4 v = *(const float4*)(x + e0);
        float s = oscale[row];
        o.x = (uint)f2bf(v.x * s) | ((uint)f2bf(v.y * s) << 16);
        o.y = (uint)f2bf(v.z * s) | ((uint)f2bf(v.w * s) << 16);
    } else {
        o.x = 0u; o.y = 0u;
    }
    *(uint2*)(xh + e0) = o;
}

// one wave per dst row, 8 edges in flight (2-deep unroll), 16B/lane gather
__global__ void k_agg(const int* __restrict__ off, const int* __restrict__ eidx,
                      const ushort* __restrict__ xh, ushort* __restrict__ agg)
{
    int wid = threadIdx.x >> 6, lane = threadIdx.x & 63;
    int r = blockIdx.x * 4 + wid;
    if (r >= NPAD) return;
    int f = lane & 15;
    int g = lane >> 4;
    float a[8] = {0.f, 0.f, 0.f, 0.f, 0.f, 0.f, 0.f, 0.f};
    if (r < N_NODES) {
        int s = off[r], e = off[r + 1];
        int i = s + g;
        for (; i + 4 < e; i += 8) {
            int sv0 = eidx[i];
            int sv1 = eidx[i + 4];
            bfx8 v0 = *(const bfx8*)(xh + (size_t)sv0 * 128 + f * 8);
            bfx8 v1 = *(const bfx8*)(xh + (size_t)sv1 * 128 + f * 8);
            #pragma unroll
            for (int k = 0; k < 8; ++k)
                a[k] += bf2f((ushort)v0[k]) + bf2f((ushort)v1[k]);
        }
        if (i < e) {
            int sv = eidx[i];
            bfx8 v = *(const bfx8*)(xh + (size_t)sv * 128 + f * 8);
            #pragma unroll
            for (int k = 0; k < 8; ++k) a[k] += bf2f((ushort)v[k]);
        }
    }
    #pragma unroll
    for (int k = 0; k < 8; ++k) {
        a[k] += __shfl_xor(a[k], 16, 64);
        a[k] += __shfl_xor(a[k], 32, 64);
    }
    if (g == 0) {
        bfx8 o;
        #pragma unroll
        for (int k = 0; k < 8; ++k) o[k] = (short)f2bf(a[k]);
        *(bfx8*)(agg + (size_t)r * 128 + f * 8) = o;
    }
}

// ---------------- all weight prep in ONE launch ----------------
__global__ void k_wprep(const float* __restrict__ gcn_w, const float* __restrict__ ff_w1,
                        const float* __restrict__ fc1_w, const float* __restrict__ ff_w2,
                        const float* __restrict__ ln_g, const float* __restrict__ ln_b,
                        const float* __restrict__ ff_b2,
                        ushort* __restrict__ gwT, ushort* __restrict__ ff1T,
                        ushort* __restrict__ fc1T, ushort* __restrict__ ff2T,
                        float* __restrict__ lnU, float* __restrict__ lnT)
{
    int bid = blockIdx.x, tid = threadIdx.x;
    if (bid < 576) {
        const float* W; ushort* Wt; int K, M, id;
        if (bid < 64)       { W = gcn_w; Wt = gwT;  K = 128; M = 128; id = bid * 256 + tid; }
        else if (bid < 320) { W = ff_w1; Wt = ff1T; K = 128; M = 512; id = (bid - 64) * 256 + tid; }
        else                { W = fc1_w; Wt = fc1T; K = 128; M = 512; id = (bid - 320) * 256 + tid; }
        int m = id / K, k = id - m * K;
        Wt[id] = f2bf(W[(size_t)k * M + m]);
    } else {
        int wid = tid >> 6, lane = tid & 63;
        int m = (bid - 576) * 4 + wid;
        float us = 0.f, ts = 0.f;
        for (int k = lane; k < 512; k += 64) {
            float w = ff_w2[(size_t)k * 128 + m];
            float gk = ln_g[k], bk = ln_b[k];
            ff2T[(size_t)m * 512 + k] = f2bf(gk * w);
            us += gk * w; ts += bk * w;
        }
        us = wave_sum(us); ts = wave_sum(ts);
        if (lane == 0) { lnU[m] = us; lnT[m] = ts + ff_b2[m]; }
    }
}

// ---------------- MEGA: GCN -> ff1(gelu) -> ff2(LN-folded, slab-fused) -> fc1(gelu, bn1 stats)
// One 128-row block does the whole chain; f never touches HBM.
// (512,4): compiler caps arch VGPR at 64 and spills h2acc to scratch; measured
// FASTER than the spill-free (512,2) variant because 2 blocks/CU stay resident.
__global__ __launch_bounds__(512, 4) void k_mega(
    const ushort* __restrict__ A1, const ushort* __restrict__ gwT,
    const ushort* __restrict__ ff1T, const ushort* __restrict__ ff2T,
    const ushort* __restrict__ fc1T, ushort* __restrict__ M1,
    const float* __restrict__ gcn_b, const float* __restrict__ ininv,
    const float* __restrict__ b1,
    const float* __restrict__ lnU, const float* __restrict__ lnT,
    const float* __restrict__ fc1_b,
    float* __restrict__ pS, float* __restrict__ pQ)
{
    __shared__ __align__(16) char smem[65536 + 2560];
    char* A2  = smem;             // 32KB: h tile, later h2 tile ([128][256B] swizzled)
    char* S   = smem + 32768;     // 16KB: phase1 As | slab stage | f/m1 C-tile
    char* Bs2 = smem + 49152;     // 16KB: ff2T slab ([128][128B])
    float* st_s = (float*)(smem + 65536);          // [2][64]
    float* st_q = (float*)(smem + 65536 + 512);    // [2][64]
    float* rS   = (float*)(smem + 65536 + 1024);   // [128]
    float* rC   = (float*)(smem + 65536 + 1536);   // [128]

    const int rb = xcd_swz(blockIdx.x, gridDim.x);
    const int tid = threadIdx.x;
    const int lane = tid & 63;
    const int wid = tid >> 6;
    const int wr = wid >> 2;
    const int wc = wid & 3;
    const int m0 = wr * 64;
    const int frl = lane & 15;
    const int kg = lane >> 4;

    // ---------- phase 1: h = (agg @ gcn_w)*ininv + gcn_b ----------
    {
        char* As = S;
        char* Bs = A2;           // A2 bytes [0,16K) dead until h written after loop
        const int n0 = wc * 32;
        fx4 acc[4][2] = {};
        const ushort* Arow0 = A1 + (size_t)(rb * 128) * 128;

        for (int kb = 0; kb < 128; kb += 64) {
            #pragma unroll
            for (int c = 0; c < 2; ++c) {
                int b = c * 8192 + tid * 16;
                int row = b >> 7;
                int cibs = (b & 127) ^ ((row & 7) << 4);
                const char* ga = (const char*)(Arow0 + (size_t)row * 128 + kb) + cibs;
                const char* gb = (const char*)(gwT + (size_t)row * 128 + kb) + cibs;
                char* la = As + c * 8192 + (wid << 10);
                char* lb = Bs + c * 8192 + (wid << 10);
                __builtin_amdgcn_global_load_lds((const AS1 void*)ga, (AS3 void*)la, 16, 0, 0);
                __builtin_amdgcn_global_load_lds((const AS1 void*)gb, (AS3 void*)lb, 16, 0, 0);
            }
            __syncthreads();
            #pragma unroll
            for (int kk = 0; kk < 2; ++kk) {
                bfx8 av[4], bv[2];
                #pragma unroll
                for (int i = 0; i < 4; ++i) {
                    int ar = m0 + i * 16 + frl;
                    av[i] = *(const bfx8*)(As + ((ar * 128 + kk * 64 + kg * 16) ^ ((ar & 7) << 4)));
                }
                #pragma unroll
                for (int j = 0; j < 2; ++j) {
                    int br = n0 + j * 16 + frl;
                    bv[j] = *(const bfx8*)(Bs + ((br * 128 + kk * 64 + kg * 16) ^ ((br & 7) << 4)));
                }
                #pragma unroll
                for (int i = 0; i < 4; ++i)
                    #pragma unroll
                    for (int j = 0; j < 2; ++j)
                        acc[i][j] = __builtin_amdgcn_mfma_f32_16x16x32_bf16(av[i], bv[j], acc[i][j], 0, 0, 0);
            }
            __syncthreads();
        }
        #pragma unroll
        for (int j = 0; j < 2; ++j) {
            int colL = n0 + j * 16 + frl;
            float c0 = gcn_b[colL];
            #pragma unroll
            for (int i = 0; i < 4; ++i) {
                #pragma unroll
                for (int r = 0; r < 4; ++r) {
                    int rowL = m0 + i * 16 + kg * 4 + r;
                    int grow = rb * 128 + rowL;
                    float v = acc[i][j][r] * ininv[grow] + c0;
                    *(ushort*)(A2 + rowL * 256 + ((colL * 2) ^ ((rowL & 7) << 4))) = f2bf(v);
                }
            }
        }
    }
    __syncthreads();

    // ---------- phase 2: f slabs + fused h2 accumulation ----------
    float rs = 0.f, rq = 0.f;
    const int rowR = tid >> 2;
    const int qR = tid & 3;
    const int n0b = wc * 16;
    const int n0h = wc * 32;
    fx4 h2acc[4][2] = {};

    for (int cb2 = 0; cb2 < 8; ++cb2) {
        #pragma unroll
        for (int c = 0; c < 2; ++c) {
            int b = c * 8192 + tid * 16;
            int row1 = b >> 8;
            int cib1 = (b & 255) ^ ((row1 & 7) << 4);
            const char* g1 = (const char*)(ff1T + (size_t)(cb2 * 64 + row1) * 128) + cib1;
            char* l1 = S + c * 8192 + (wid << 10);
            __builtin_amdgcn_global_load_lds((const AS1 void*)g1, (AS3 void*)l1, 16, 0, 0);
            int row2 = b >> 7;
            int cib2 = (b & 127) ^ ((row2 & 7) << 4);
            const char* g2 = (const char*)ff2T + (size_t)row2 * 1024 + cb2 * 128 + cib2;
            char* l2 = Bs2 + c * 8192 + (wid << 10);
            __builtin_amdgcn_global_load_lds((const AS1 void*)g2, (AS3 void*)l2, 16, 0, 0);
        }
        __syncthreads();

        // f = h(A2) @ ff1T-slab(S)
        fx4 fa[4] = {};
        #pragma unroll
        for (int kk = 0; kk < 4; ++kk) {
            int c2 = kk * 64 + kg * 16;
            bfx8 av[4], bv;
            #pragma unroll
            for (int i = 0; i < 4; ++i) {
                int ar = m0 + i * 16 + frl;
                av[i] = *(const bfx8*)(A2 + ar * 256 + (c2 ^ ((ar & 7) << 4)));
            }
            {
                int br = n0b + frl;
                bv = *(const bfx8*)(S + br * 256 + (c2 ^ ((br & 7) << 4)));
            }
            #pragma unroll
            for (int i = 0; i < 4; ++i)
                fa[i] = __builtin_amdgcn_mfma_f32_16x16x32_bf16(av[i], bv, fa[i], 0, 0, 0);
        }
        __syncthreads();   // S reads done

        // gelu(f + b1) -> C-tile [128][128B] in S
        {
            int colL = n0b + frl;
            float bcol = b1[cb2 * 64 + colL];
            #pragma unroll
            for (int i = 0; i < 4; ++i) {
                #pragma unroll
                for (int r = 0; r < 4; ++r) {
                    float v = gelu_fast(fa[i][r] + bcol);
                    int rowL = m0 + i * 16 + kg * 4 + r;
                    *(ushort*)(S + rowL * 128 + ((colL * 2) ^ ((rowL & 7) << 4))) = f2bf(v);
                }
            }
        }
        __syncthreads();   // C-tile visible

        // h2acc += f(S) @ ff2T-slab(Bs2)  [K=64]; row stats from S
        #pragma unroll
        for (int kk2 = 0; kk2 < 2; ++kk2) {
            int c2b = kk2 * 64 + kg * 16;
            bfx8 av2[4], bv2[2];
            #pragma unroll
            for (int i = 0; i < 4; ++i) {
                int ar = m0 + i * 16 + frl;
                av2[i] = *(const bfx8*)(S + ar * 128 + (c2b ^ ((ar & 7) << 4)));
            }
            #pragma unroll
            for (int j = 0; j < 2; ++j) {
                int br = n0h + j * 16 + frl;
                bv2[j] = *(const bfx8*)(Bs2 + br * 128 + (c2b ^ ((br & 7) << 4)));
            }
            #pragma unroll
            for (int i = 0; i < 4; ++i)
                #pragma unroll
                for (int j = 0; j < 2; ++j)
                    h2acc[i][j] = __builtin_amdgcn_mfma_f32_16x16x32_bf16(av2[i], bv2[j], h2acc[i][j], 0, 0, 0);
        }
        #pragma unroll
        for (int ss = 0; ss < 2; ++ss) {
            int boff = rowR * 128 + ((qR * 32 + ss * 16) ^ ((rowR & 7) << 4));
            bfx8 v = *(const bfx8*)(S + boff);
            #pragma unroll
            for (int k2 = 0; k2 < 8; ++k2) {
                float f = bf2f((ushort)v[k2]);
                rs += f; rq += f * f;
            }
        }
        __syncthreads();   // S, Bs2 reads done before next slab
    }

    // row LN stats -> LDS
    rs += __shfl_xor(rs, 1, 64); rs += __shfl_xor(rs, 2, 64);
    rq += __shfl_xor(rq, 1, 64); rq += __shfl_xor(rq, 2, 64);
    if (qR == 0) {
        float mean = rs * (1.f / 512.f);
        float var = fmaxf(rq * (1.f / 512.f) - mean * mean, 0.f);
        float sr = rsqrtf(var + 1e-5f);
        rS[rowR] = sr;
        rC[rowR] = -mean * sr;
    }
    __syncthreads();

    // h2 epilogue: h2 = sr*h2acc + cr*u_col + t_col -> A2 (h dead)
    #pragma unroll
    for (int j = 0; j < 2; ++j) {
        int colL = n0h + j * 16 + frl;
        float uc = lnU[colL];
        float tc = lnT[colL];
        #pragma unroll
        for (int i = 0; i < 4; ++i) {
            #pragma unroll
            for (int r = 0; r < 4; ++r) {
                int rowL = m0 + i * 16 + kg * 4 + r;
                float v = rS[rowL] * h2acc[i][j][r] + rC[rowL] * uc + tc;
                *(ushort*)(A2 + rowL * 256 + ((colL * 2) ^ ((rowL & 7) << 4))) = f2bf(v);
            }
        }
    }
    __syncthreads();

    // ---------- phase 3: m1 = gelu(h2 @ fc1T + b) + bn1 col partials ----------
    for (int cb3 = 0; cb3 < 8; ++cb3) {
        #pragma unroll
        for (int c = 0; c < 2; ++c) {
            int b = c * 8192 + tid * 16;
            int row = b >> 8;
            int cibs = (b & 255) ^ ((row & 7) << 4);
            const char* gb = (const char*)(fc1T + (size_t)(cb3 * 64 + row) * 128) + cibs;
            char* lb = S + c * 8192 + (wid << 10);
            __builtin_amdgcn_global_load_lds((const AS1 void*)gb, (AS3 void*)lb, 16, 0, 0);
        }
        __syncthreads();

        fx4 ma[4] = {};
        #pragma unroll
        for (int kk = 0; kk < 4; ++kk) {
            int c2 = kk * 64 + kg * 16;
            bfx8 av[4], bv;
            #pragma unroll
            for (int i = 0; i < 4; ++i) {
                int ar = m0 + i * 16 + frl;
                av[i] = *(const bfx8*)(A2 + ar * 256 + (c2 ^ ((ar & 7) << 4)));
            }
            {
                int br = n0b + frl;
                bv = *(const bfx8*)(S + br * 256 + (c2 ^ ((br & 7) << 4)));
            }
            #pragma unroll
            for (int i = 0; i < 4; ++i)
                ma[i] = __builtin_amdgcn_mfma_f32_16x16x32_bf16(av[i], bv, ma[i], 0, 0, 0);
        }
        __syncthreads();

        {
            int colL = n0b + frl;
            float bcol = fc1_b[cb3 * 64 + colL];
            float sL = 0.f, qL = 0.f;
            #pragma unroll
            for (int i = 0; i < 4; ++i) {
                #pragma unroll
                for (int r = 0; r < 4; ++r) {
                    float v = gelu_fast(ma[i][r] + bcol);
                    int rowL = m0 + i * 16 + kg * 4 + r;
                    if (rb * 128 + rowL < N_NODES) { sL += v; qL += v * v; }
                    *(ushort*)(S + rowL * 128 + ((colL * 2) ^ ((rowL & 7) << 4))) = f2bf(v);
                }
            }
            sL += __shfl_xor(sL, 16, 64); sL += __shfl_xor(sL, 32, 64);
            qL += __shfl_xor(qL, 16, 64); qL += __shfl_xor(qL, 32, 64);
            if (kg == 0) {
                st_s[wr * 64 + colL] = sL;
                st_q[wr * 64 + colL] = qL;
            }
        }
        __syncthreads();

        {
            int r2 = tid >> 3;
            int s2 = tid & 7;
            #pragma unroll
            for (int pass = 0; pass < 2; ++pass) {
                int rowL = pass * 64 + r2;
                int boff = rowL * 128 + ((s2 * 16) ^ ((rowL & 7) << 4));
                bfx8 v = *(const bfx8*)(S + boff);
                *(bfx8*)((char*)(M1 + (size_t)(rb * 128 + rowL) * 512 + cb3 * 64) + s2 * 16) = v;
            }
        }
        if (tid < 64) {
            size_t pidx = ((size_t)rb * 4 + (cb3 >> 1)) * 128 + (cb3 & 1) * 64 + tid;
            pS[pidx] = st_s[tid] + st_s[64 + tid];
            pQ[pidx] = st_q[tid] + st_q[64 + tid];
        }
        __syncthreads();
    }
}

// ---------------- plain GEMM (fc2, fc3), 8-wave 512-thread ----------------
template <int EPI, int STATS>
__global__ __launch_bounds__(512, 4) void k_gemm(
    const ushort* __restrict__ A, const ushort* __restrict__ Bt,
    ushort* __restrict__ C, int K, int M,
    const float* __restrict__ colv0, const float* __restrict__ rowv0,
    float* __restrict__ pS, float* __restrict__ pQ, int grb0)
{
    __shared__ __align__(16) char smem[32768 + (STATS == 1 ? 2048 : 0)];
    char* AsB = smem;
    char* BsB = smem + 16384;
    float* st_s = (float*)(smem + 32768);
    float* st_q = (float*)(smem + 32768 + 1024);

    const int nwg = gridDim.x;
    const int wgid = xcd_swz(blockIdx.x, nwg);
    const int nCB = M >> 7;
    const int cb = wgid % nCB;
    const int rb = wgid / nCB;
    const int tid = threadIdx.x;
    const int lane = tid & 63;
    const int wid = tid >> 6;
    const int wr = wid >> 2;
    const int wc = wid & 3;
    const int m0 = wr * 64;
    const int n0 = wc * 32;
    const int frl = lane & 15;
    const int kg = lane >> 4;

    fx4 acc[4][2] = {};

    const ushort* Arow0 = A + (size_t)(rb * 128) * K;
    const ushort* Brow0 = Bt + (size_t)(cb * 128) * K;

    for (int kb = 0; kb < K; kb += 64) {
        #pragma unroll
        for (int c = 0; c < 2; ++c) {
            int b = c * 8192 + tid * 16;
            int row = b >> 7;
            int cibs = (b & 127) ^ ((row & 7) << 4);
            const char* ga = (const char*)(Arow0 + (size_t)row * K + kb) + cibs;
            const char* gb = (const char*)(Brow0 + (size_t)row * K + kb) + cibs;
            char* la = AsB + c * 8192 + (wid << 10);
            char* lb = BsB + c * 8192 + (wid << 10);
            __builtin_amdgcn_global_load_lds((const AS1 void*)ga, (AS3 void*)la, 16, 0, 0);
            __builtin_amdgcn_global_load_lds((const AS1 void*)gb, (AS3 void*)lb, 16, 0, 0);
        }
        __syncthreads();
        #pragma unroll
        for (int kk = 0; kk < 2; ++kk) {
            bfx8 av[4], bv[2];
            #pragma unroll
            for (int i = 0; i < 4; ++i) {
                int ar = m0 + i * 16 + frl;
                av[i] = *(const bfx8*)(AsB + ((ar * 128 + kk * 64 + kg * 16) ^ ((ar & 7) << 4)));
            }
            #pragma unroll
            for (int j = 0; j < 2; ++j) {
                int br = n0 + j * 16 + frl;
                bv[j] = *(const bfx8*)(BsB + ((br * 128 + kk * 64 + kg * 16) ^ ((br & 7) << 4)));
            }
            #pragma unroll
            for (int i = 0; i < 4; ++i)
                #pragma unroll
                for (int j = 0; j < 2; ++j)
                    acc[i][j] = __builtin_amdgcn_mfma_f32_16x16x32_bf16(av[i], bv[j], acc[i][j], 0, 0, 0);
        }
        __syncthreads();
    }

    #pragma unroll
    for (int j = 0; j < 2; ++j) {
        int colL = n0 + j * 16 + frl;
        float c0 = colv0[cb * 128 + colL];
        float sL = 0.f, qL = 0.f;
        #pragma unroll
        for (int i = 0; i < 4; ++i) {
            #pragma unroll
            for (int r = 0; r < 4; ++r) {
                float v = acc[i][j][r];
                int rowL = m0 + i * 16 + kg * 4 + r;
                int grow = (grb0 + rb) * 128 + rowL;
                if (EPI == 0) v = v * rowv0[grow] + c0;
                else          v = gelu_fast(v + c0);
                if (STATS == 1) {
                    if (grow < N_NODES) { sL += v; qL += v * v; }
                }
                *(ushort*)(smem + rowL * 256 + ((colL * 2) ^ ((rowL & 7) << 4))) = f2bf(v);
            }
        }
        if (STATS == 1) {
            sL += __shfl_xor(sL, 16, 64); sL += __shfl_xor(sL, 32, 64);
            qL += __shfl_xor(qL, 16, 64); qL += __shfl_xor(qL, 32, 64);
            if (kg == 0) {
                st_s[wr * 128 + colL] = sL;
                st_q[wr * 128 + colL] = qL;
            }
        }
    }
    __syncthreads();
    {
        int r2 = tid >> 4;
        int s2 = tid & 15;
        #pragma unroll
        for (int pass = 0; pass < 4; ++pass) {
            int rowL = pass * 32 + r2;
            int boff = rowL * 256 + ((s2 * 16) ^ ((rowL & 7) << 4));
            bfx8 v = *(const bfx8*)(smem + boff);
            *(bfx8*)((char*)(C + (size_t)(rb * 128 + rowL) * M + cb * 128) + s2 * 16) = v;
        }
    }
    if (STATS == 1 && tid < 128) {
        size_t pidx = ((size_t)(grb0 + rb) * nCB + cb) * 128 + tid;
        pS[pidx] = st_s[tid] + st_s[128 + tid];
        pQ[pidx] = st_q[tid] + st_q[128 + tid];
    }
}

// merge col partials -> sums: one wave per column
__global__ void k_colmerge(const float* __restrict__ pS, const float* __restrict__ pQ,
                           float* __restrict__ oS, float* __restrict__ oQ, int M)
{
    int wid = threadIdx.x >> 6, lane = threadIdx.x & 63;
    int m = blockIdx.x * 4 + wid;
    if (m >= M) return;
    int nCB = M >> 7, cb = m >> 7, colL = m & 127;
    float s = 0.f, q = 0.f;
    for (int rb = lane; rb < NRB; rb += 64) {
        size_t idx = ((size_t)rb * nCB + cb) * 128 + colL;
        s += pS[idx]; q += pQ[idx];
    }
    s = wave_sum(s); q = wave_sum(q);
    if (lane == 0) { oS[m] = s; oQ[m] = q; }
}

// fold BN(prev-layer cols) into next weight
__global__ void k_fold(const float* __restrict__ W, const float* __restrict__ bw,
                       const float* __restrict__ g, const float* __restrict__ bb,
                       const float* __restrict__ sum, const float* __restrict__ sqs,
                       int K, int M, ushort* __restrict__ WtO, float* __restrict__ bO)
{
    int wid = threadIdx.x >> 6, lane = threadIdx.x & 63;
    int m = blockIdx.x * 4 + wid;
    if (m >= M) return;
    float acc = 0.f;
    for (int k = lane; k < K; k += 64) {
        float mean = sum[k] * (1.f / (float)N_NODES);
        float var = sqs[k] * (1.f / (float)N_NODES) - mean * mean;
        float s = g[k] * rsqrtf(var + 1e-5f);
        float t = bb[k] - mean * s;
        float w = W[(size_t)k * M + m];
        WtO[(size_t)m * K + k] = f2bf(w * s);
        acc += t * w;
    }
    acc = wave_sum(acc);
    if (lane == 0) bO[m] = bw[m] + acc;
}

// out[r] = dot(m3[r,:128], w4) + b4
__global__ void k_out(const ushort* __restrict__ m3, const ushort* __restrict__ w4,
                      const float* __restrict__ b4, float* __restrict__ out)
{
    int wid = threadIdx.x >> 6, lane = threadIdx.x & 63;
    int r = blockIdx.x * 4 + wid;
    if (r >= N_NODES) return;
    uint u = *(const uint*)(m3 + (size_t)r * 128 + lane * 2);
    uint w = *(const uint*)(w4 + lane * 2);
    float acc = bf2f((ushort)(u & 0xffffu)) * bf2f((ushort)(w & 0xffffu))
              + bf2f((ushort)(u >> 16)) * bf2f((ushort)(w >> 16));
    acc = wave_sum(acc);
    if (lane == 0) out[r] = acc + b4[0];
}

extern "C" void kernel_launch(void* const* d_in, const int* in_sizes, int n_in,
                              void* d_out, int out_size, void* d_ws, size_t ws_size,
                              hipStream_t stream)
{
    const float* x     = (const float*)d_in[0];
    const int*   src   = (const int*)d_in[1];
    const int*   dst   = (const int*)d_in[2];
    const float* gcn_w = (const float*)d_in[3];
    const float* gcn_b = (const float*)d_in[4];
    const float* ff_w1 = (const float*)d_in[5];
    const float* ff_b1 = (const float*)d_in[6];
    const float* ln_g  = (const float*)d_in[7];
    const float* ln_b  = (const float*)d_in[8];
    const float* ff_w2 = (const float*)d_in[9];
    const float* ff_b2 = (const float*)d_in[10];
    const float* fc1_w = (const float*)d_in[11];
    const float* fc1_b = (const float*)d_in[12];
    const float* bn1_g = (const float*)d_in[13];
    const float* bn1_b = (const float*)d_in[14];
    const float* fc2_w = (const float*)d_in[15];
    const float* fc2_b = (const float*)d_in[16];
    const float* bn2_g = (const float*)d_in[17];
    const float* bn2_b = (const float*)d_in[18];
    const float* fc3_w = (const float*)d_in[19];
    const float* fc3_b = (const float*)d_in[20];
    const float* bn3_g = (const float*)d_in[21];
    const float* bn3_b = (const float*)d_in[22];
    const float* fc4_w = (const float*)d_in[23];
    const float* fc4_b = (const float*)d_in[24];
    float* out = (float*)d_out;
    (void)in_sizes; (void)n_in; (void)out_size;

    char* base = (char*)d_ws;
    char* p = base;
    auto alloc = [&](size_t bytes) -> char* {
        char* r = p;
        p += (bytes + 255) & ~(size_t)255;
        return r;
    };
    int*    inc    = (int*)alloc((size_t)NPAD * 4);
    int*    coff   = (int*)alloc(((size_t)NPAD + 1) * 4);
    int*    btot   = (int*)alloc(128 * 4);
    int*    gcur   = (int*)alloc(256 * 4);
    int*    eidx   = (int*)alloc((size_t)E_EDGES * 4);
    float*  oscale = (float*)alloc((size_t)NPAD * 4);
    float*  ininv  = (float*)alloc((size_t)NPAD * 4);
    float*  bns    = (float*)alloc(6 * 512 * 4);
    float*  b2p    = (float*)alloc(512 * 4);
    float*  b3p    = (float*)alloc(128 * 4);
    float*  b4p    = (float*)alloc(4);
    float*  lnU    = (float*)alloc(128 * 4);
    float*  lnT    = (float*)alloc(128 * 4);
    float*  pS     = (float*)alloc((size_t)4 * NPAD * 4);
    float*  pQ     = (float*)alloc((size_t)4 * NPAD * 4);
    ushort* gwT    = (ushort*)alloc(128 * 128 * 2);
    ushort* ff1T   = (ushort*)alloc(512 * 128 * 2);
    ushort* ff2T   = (ushort*)alloc(128 * 512 * 2);
    ushort* fc1T   = (ushort*)alloc(512 * 128 * 2);
    ushort* fc2T   = (ushort*)alloc(512 * 512 * 2);
    ushort* fc3T   = (ushort*)alloc(128 * 512 * 2);
    ushort* w4t    = (ushort*)alloc(128 * 2);
    ushort* buf1   = (ushort*)alloc((size_t)NPAD * 128 * 2);  // agg -> (fc2 chunk tmp) -> m3
    ushort* bufC   = (ushort*)alloc((size_t)NPAD * 512 * 2);  // hist parts / edge tmp -> xh -> m1 [-> m2]

    size_t used = (size_t)(p - base);
    bool   sep  = (used + (size_t)NPAD * 512 * 2) <= ws_size;
    ushort* m2  = sep ? (ushort*)alloc((size_t)NPAD * 512 * 2) : bufC;

    uint* partO = (uint*)bufC;
    uint* partI = partO + (size_t)HNR * HP * (HRSZ / 2);
    uint* etmp  = (uint*)bufC;
    ushort* xh  = bufC;
    ushort* agg = buf1;

    float* bn1s = bns;
    float* bn1q = bns + 512;
    float* bn2s = bns + 1024;
    float* bn2q = bns + 1536;
    float* bn3s = bns + 2048;
    float* bn3q = bns + 2560;

    k_hist2<<<2 * HNR * HP, 256, 0, stream>>>(src, dst, partO, partI);
    k_degmerge<<<(NPAD + 255) / 256, 256, 0, stream>>>(partO, partI, inc, oscale, ininv);
    k_scan1<<<NBLK_SCAN, 1024, 0, stream>>>(inc, coff, btot);
    k_scan2<<<1, 128, 0, stream>>>(btot);
    k_scan3<<<(N_NODES + 255) / 256, 256, 0, stream>>>(coff, btot, gcur);
    k_part<<<E_EDGES / PCHK, 256, 0, stream>>>(src, dst, gcur, etmp);
    k_fill2<<<NBK, 256, 0, stream>>>(etmp, coff, eidx);
    k_xhat<<<(NPAD / 256) * 32, 256, 0, stream>>>(x, oscale, xh);
    k_agg<<<NPAD / 4, 256, 0, stream>>>(coff, eidx, xh, agg);

    k_wprep<<<608, 256, 0, stream>>>(gcn_w, ff_w1, fc1_w, ff_w2, ln_g, ln_b, ff_b2,
                                     gwT, ff1T, fc1T, ff2T, lnU, lnT);

    // MEGA: GCN -> ff1(gelu) -> ff2(LN folded, slab-fused, no f round-trip) -> fc1(gelu)+bn1
    k_mega<<<NRB, 512, 0, stream>>>(agg, gwT, ff1T, ff2T, fc1T, bufC,
                                    gcn_b, ininv, ff_b1, lnU, lnT, fc1_b, pS, pQ);
    k_colmerge<<<128, 256, 0, stream>>>(pS, pQ, bn1s, bn1q, 512);
    k_fold<<<512 / 4, 256, 0, stream>>>(fc2_w, fc2_b, bn1_g, bn1_b, bn1s, bn1q, 512, 512, fc2T, b2p);
    // m2 = gelu(bn1(m1) @ fc2 + b) + bn2 partials
    if (sep) {
        k_gemm<1, 1><<<4 * NRB, 512, 0, stream>>>(bufC, fc2T, m2, 512, 512,
                                                  b2p, nullptr, pS, pQ, 0);
    } else {
        const int cOff[6] = {0, 195, 390, 585, 780, 782};
        for (int c = 0; c < 5; ++c) {
            int rb0 = cOff[c], nrb = cOff[c + 1] - rb0;
            k_gemm<1, 1><<<nrb * 4, 512, 0, stream>>>(bufC + (size_t)rb0 * 128 * 512, fc2T,
                                                      buf1, 512, 512,
                                                      b2p, nullptr, pS, pQ, rb0);
            hipMemcpyAsync(bufC + (size_t)rb0 * 128 * 512, buf1,
                           (size_t)nrb * 128 * 512 * 2, hipMemcpyDeviceToDevice, stream);
        }
    }
    k_colmerge<<<128, 256, 0, stream>>>(pS, pQ, bn2s, bn2q, 512);
    k_fold<<<128 / 4, 256, 0, stream>>>(fc3_w, fc3_b, bn2_g, bn2_b, bn2s, bn2q, 512, 128, fc3T, b3p);
    // m3 = gelu(bn2(m2) @ fc3 + b) + bn3 partials
    k_gemm<1, 1><<<NRB, 512, 0, stream>>>(m2, fc3T, buf1, 512, 128,
                                          b3p, nullptr, pS, pQ, 0);
    k_colmerge<<<32, 256, 0, stream>>>(pS, pQ, bn3s, bn3q, 128);
    k_fold<<<1, 256, 0, stream>>>(fc4_w, fc4_b, bn3_g, bn3_b, bn3s, bn3q, 128, 1, w4t, b4p);
    k_out<<<N_NODES / 4, 256, 0, stream>>>(buf1, w4t, b4p, out);
}